// Round 4
// baseline (906.803 us; speedup 1.0000x reference)
//
#include <hip/hip_runtime.h>
#include <hip/hip_bf16.h>
#include <stdio.h>

// BNBQuantizedLinear: out = x @ dequant(w)^T + bias
// x [8192,4096] f32, w [11008,4096] f32 (group-128 affine fake-quant), out f32.
// Round 4: register-level software pipeline. Round-3 post-mortem: 2756 cyc/tile
// = LDS-read phase (1152) + MFMA phase (1242) run SERIALLY (frag loads feed the
// MFMAs directly; 1 block/CU so no inter-block overlap). Fix: per tile, load
// cur-tile af[4..7] under MFMA half 1 (which consumes frags prefetched last
// tile), prefetch next-tile af[0..3]+B under MFMA half 2. Only B-frags are
// double-buffered (+16 VGPR); af reused in place (WAR resolves at issue).
// 4-deep LDS ring, counted vmcnt(8), T1 XCD swizzle, T2 source-side XOR
// swizzle (bank conflicts measured 0) all retained.

typedef unsigned short u16;
typedef __attribute__((ext_vector_type(8))) short short8;
typedef __attribute__((ext_vector_type(8))) unsigned short ushort8;
typedef __attribute__((ext_vector_type(4))) float f32x4;

constexpr int Mdim = 8192;
constexpr int Ndim = 11008;
constexpr int Kdim = 4096;

#define BK 32
#define NTILES 128          // Kdim / BK
#define TILE_ELEMS 8192     // 256 rows * 32 cols u16 per K-tile buffer (16 KB)

__device__ __forceinline__ u16 f2bf(float f) {
  union { float f; unsigned u; } c; c.f = f;
  unsigned r = c.u + 0x7FFFu + ((c.u >> 16) & 1u);  // RTNE
  return (u16)(r >> 16);
}

// ---------------- kernel 1: group-dequant weight -> bf16 ----------------
__global__ __launch_bounds__(256) void k_dequant_w(const float* __restrict__ w,
                                                   u16* __restrict__ wb) {
  const int lane = threadIdx.x & 63;
  const long g = (long)blockIdx.x * 4 + (threadIdx.x >> 6);
  const long base = g * 128 + lane * 2;
  const float2 v = *(const float2*)(w + base);
  float mn = fminf(v.x, v.y), mx = fmaxf(v.x, v.y);
#pragma unroll
  for (int off = 32; off > 0; off >>= 1) {
    mn = fminf(mn, __shfl_xor(mn, off));
    mx = fmaxf(mx, __shfl_xor(mx, off));
  }
  const float scale = (mx - mn) / 15.0f;
  const float zp = -mn / scale;
  const u16 o0 = f2bf((v.x - zp) * scale);
  const u16 o1 = f2bf((v.y - zp) * scale);
  *(unsigned*)(wb + base) = (unsigned)o0 | ((unsigned)o1 << 16);
}

// ---------------- kernel 2: x f32 -> bf16 ----------------
__global__ __launch_bounds__(256) void k_cvt_x(const float* __restrict__ x,
                                               u16* __restrict__ xb) {
  const long i = ((long)blockIdx.x * 256 + threadIdx.x) * 8;
  const float4 v0 = *(const float4*)(x + i);
  const float4 v1 = *(const float4*)(x + i + 4);
  ushort8 o;
  o[0] = f2bf(v0.x); o[1] = f2bf(v0.y); o[2] = f2bf(v0.z); o[3] = f2bf(v0.w);
  o[4] = f2bf(v1.x); o[5] = f2bf(v1.y); o[6] = f2bf(v1.z); o[7] = f2bf(v1.w);
  *(ushort8*)(xb + i) = o;
}

// ---------------- kernel 3: deep-pipelined 256x256 bf16 GEMM ----------------
__device__ __forceinline__ void async_ld16(const u16* g, u16* l) {
  __builtin_amdgcn_global_load_lds(
      (const __attribute__((address_space(1))) void*)g,
      (__attribute__((address_space(3))) void*)l, 16, 0, 0);
}

__global__ __launch_bounds__(512, 2) void k_gemm(const u16* __restrict__ A,
                                                 const u16* __restrict__ B,
                                                 const float* __restrict__ bias,
                                                 float* __restrict__ C) {
  __shared__ u16 As[4 * TILE_ELEMS];   // 64 KB
  __shared__ u16 Bs[4 * TILE_ELEMS];   // 64 KB

  const int t = threadIdx.x;
  const int wave = t >> 6;        // 0..7
  const int lane = t & 63;
  const int wm = wave >> 2;       // 2(M) x 4(N) wave grid; wave owns 128x64 out
  const int wn = wave & 3;
  const int r  = lane & 15;
  const int kg = lane >> 4;
  const int slot = kg ^ ((r >> 1) & 3);

  // bijective XCD swizzle: 1376 workgroups = 8 XCDs x 172
  const int bid = blockIdx.x;
  const int wg = (bid & 7) * 172 + (bid >> 3);
  const int by = wg / 43;
  const int bx = wg % 43;
  const long bm0 = (long)by * 256;
  const long bn0 = (long)bx * 256;

  // staging: one issue = 512 thr x 16B = 8 KB = 128 rows. 2 issues per matrix.
  const int s_row  = t >> 2;
  const int s_slot = (t & 3) ^ ((t >> 3) & 3);
  const u16* a_src = A + (bm0 + s_row) * Kdim + s_slot * 8;
  const u16* b_src = B + (bn0 + s_row) * Kdim + s_slot * 8;
  const int st_off = wave * 512;

  const int a_roff = (wm * 128 + r) * 32 + slot * 8;  // + mf*512
  const int b_roff = (wn * 64  + r) * 32 + slot * 8;  // + nf*512

  f32x4 acc[8][4] = {};
  short8 af[8];     // af[0..3]: cur-tile (prefetched last tile); af[4..7]: loaded in-tile
  short8 bf0[4], bf1[4];  // B-frags, double-buffered by tile parity

#define STAGE_A(TAU, BUF) do {                                    \
    const u16* g_ = a_src + (size_t)(TAU) * 32;                   \
    u16* l_ = As + (BUF) * TILE_ELEMS + st_off;                   \
    async_ld16(g_, l_);                                           \
    async_ld16(g_ + (size_t)128 * Kdim, l_ + 4096);               \
  } while (0)
#define STAGE_B(TAU, BUF) do {                                    \
    const u16* g_ = b_src + (size_t)(TAU) * 32;                   \
    u16* l_ = Bs + (BUF) * TILE_ELEMS + st_off;                   \
    async_ld16(g_, l_);                                           \
    async_ld16(g_ + (size_t)128 * Kdim, l_ + 4096);               \
  } while (0)

#define VM8 asm volatile("s_waitcnt vmcnt(8)" ::: "memory")
#define VM4 asm volatile("s_waitcnt vmcnt(4)" ::: "memory")
#define VM0 asm volatile("s_waitcnt vmcnt(0)" ::: "memory")
#define VMNONE (void)0

  // Hazard ledger (2 barriers/tile):
  //  - VM8 at tile tau drains tau+1's 4 stages (per-wave); B1 makes ALL waves'
  //    tau+1 data visible -> prefetch reads of buf (tau+1)&3 after B1 are safe.
  //  - Reads of buf X=(tau+1)&3 (prefetch at tau) complete before their lgkm
  //    drain at tau+1's MFMAs, which precedes tau+1's B2. X is re-staged at
  //    tile tau+2 top (stages tau+5, (tau+5)&3==X), which is after tau+1's B2
  //    -> no write-before-read.
  //  - af[0..3] overwrite (prefetch) is after MFMA half 1 issued (WAR at issue).
#define KTILE(TAU, BCUR, BNXT, DO_STAGE, VMSTMT, DO_PREF, DO_B1) do {        \
    if (DO_STAGE) { STAGE_A((TAU)+3, ((TAU)+3)&3);                           \
                    STAGE_B((TAU)+3, ((TAU)+3)&3); }                         \
    VMSTMT;                                                                  \
    if (DO_B1) __builtin_amdgcn_s_barrier();                                 \
    { const u16* Ac_ = As + ((TAU)&3) * TILE_ELEMS;                          \
      _Pragma("unroll")                                                      \
      for (int mf = 4; mf < 8; ++mf)                                         \
        af[mf] = *(const short8*)&Ac_[a_roff + mf*512]; }                    \
    __builtin_amdgcn_s_setprio(1);                                           \
    _Pragma("unroll")                                                        \
    for (int mf = 0; mf < 4; ++mf)                                           \
      _Pragma("unroll")                                                      \
      for (int nf = 0; nf < 4; ++nf)                                         \
        acc[mf][nf] = __builtin_amdgcn_mfma_f32_16x16x32_bf16(af[mf], BCUR[nf], acc[mf][nf], 0, 0, 0); \
    __builtin_amdgcn_s_setprio(0);                                           \
    if (DO_PREF) {                                                           \
      const u16* An_ = As + (((TAU)+1)&3) * TILE_ELEMS;                      \
      const u16* Bn_ = Bs + (((TAU)+1)&3) * TILE_ELEMS;                      \
      _Pragma("unroll")                                                      \
      for (int mf = 0; mf < 4; ++mf)                                         \
        af[mf] = *(const short8*)&An_[a_roff + mf*512];                      \
      _Pragma("unroll")                                                      \
      for (int nf = 0; nf < 4; ++nf)                                         \
        BNXT[nf] = *(const short8*)&Bn_[b_roff + nf*512];                    \
    }                                                                        \
    __builtin_amdgcn_s_setprio(1);                                           \
    _Pragma("unroll")                                                        \
    for (int mf = 4; mf < 8; ++mf)                                           \
      _Pragma("unroll")                                                      \
      for (int nf = 0; nf < 4; ++nf)                                         \
        acc[mf][nf] = __builtin_amdgcn_mfma_f32_16x16x32_bf16(af[mf], BCUR[nf], acc[mf][nf], 0, 0, 0); \
    __builtin_amdgcn_s_setprio(0);                                           \
    __builtin_amdgcn_s_barrier();  /* B2 */                                  \
  } while (0)

  // prologue: stage tiles 0,1,2; land tile 0; prefetch tile-0 frags
  STAGE_A(0, 0); STAGE_B(0, 0);
  STAGE_A(1, 1); STAGE_B(1, 1);
  STAGE_A(2, 2); STAGE_B(2, 2);
  VM8;                              // drains tile 0 (12 -> 8 outstanding)
  __builtin_amdgcn_s_barrier();
  {
    const u16* An_ = As;
    const u16* Bn_ = Bs;
#pragma unroll
    for (int mf = 0; mf < 4; ++mf) af[mf] = *(const short8*)&An_[a_roff + mf*512];
#pragma unroll
    for (int nf = 0; nf < 4; ++nf) bf0[nf] = *(const short8*)&Bn_[b_roff + nf*512];
  }

  for (int tau = 0; tau < NTILES - 4; tau += 4) {
    KTILE(tau + 0, bf0, bf1, 1, VM8, 1, 1);
    KTILE(tau + 1, bf1, bf0, 1, VM8, 1, 1);
    KTILE(tau + 2, bf0, bf1, 1, VM8, 1, 1);
    KTILE(tau + 3, bf1, bf0, 1, VM8, 1, 1);
  }
  KTILE(124, bf0, bf1, 1, VM8,    1, 1);   // stages tile 127
  KTILE(125, bf1, bf0, 0, VM4,    1, 1);
  KTILE(126, bf0, bf1, 0, VM0,    1, 1);
  KTILE(127, bf1, bf0, 0, VMNONE, 0, 0);

  // epilogue: C/D layout col = lane&15, row = (lane>>4)*4 + j
#pragma unroll
  for (int nf = 0; nf < 4; ++nf) {
    const long col = bn0 + wn * 64 + nf * 16 + r;
    const float bv = bias[col];
#pragma unroll
    for (int mf = 0; mf < 8; ++mf) {
      const long row0 = bm0 + wm * 128 + mf * 16 + kg * 4;
#pragma unroll
      for (int j = 0; j < 4; ++j)
        C[(row0 + j) * Ndim + col] = acc[mf][nf][j] + bv;
    }
  }
}

extern "C" void kernel_launch(void* const* d_in, const int* in_sizes, int n_in,
                              void* d_out, int out_size, void* d_ws, size_t ws_size,
                              hipStream_t stream) {
  const float* x    = (const float*)d_in[0];
  const float* w    = (const float*)d_in[1];
  const float* bias = (const float*)d_in[2];
  float* out = (float*)d_out;

  const size_t xb_elems = (size_t)Mdim * Kdim;
  const size_t wb_elems = (size_t)Ndim * Kdim;
  const size_t need = (xb_elems + wb_elems) * sizeof(u16);
  if (ws_size < need) {
    fprintf(stderr, "kernel_launch: ws too small (%zu < %zu)\n", ws_size, need);
    return;
  }
  u16* xb = (u16*)d_ws;
  u16* wb = xb + xb_elems;

  k_dequant_w<<<(int)(wb_elems / 128 / 4), 256, 0, stream>>>(w, wb);
  k_cvt_x<<<(int)(xb_elems / (8 * 256)), 256, 0, stream>>>(x, xb);

  k_gemm<<<(Ndim / 256) * (Mdim / 256), 512, 0, stream>>>(xb, wb, bias, out);
}

// Round 5
// 897.118 us; speedup vs baseline: 1.0108x; 1.0108x over previous
//
#include <hip/hip_runtime.h>
#include <hip/hip_bf16.h>
#include <stdio.h>

// BNBQuantizedLinear: out = x @ dequant(w)^T + bias
// x [8192,4096] f32, w [11008,4096] f32 (group-128 affine fake-quant), out f32.
// Round 5: break the 1-block/CU read->MFMA convoy. Tile 256x128, 4 waves
// (each 128x64, same fragment math as rounds 2-4), 3-buffer LDS ring (72 KB)
// -> 2 blocks/CU. Two barrier domains per CU let block A's LDS-read phase
// overlap block B's MFMA phase (m97/m114 mechanism). Counted vmcnt(6)/tile,
// stage t+2 at top of tile t (buf freed at t-1 end). T1 XCD swizzle + T2
// source-side XOR swizzle (0 conflicts measured) retained.

typedef unsigned short u16;
typedef __attribute__((ext_vector_type(8))) short short8;
typedef __attribute__((ext_vector_type(8))) unsigned short ushort8;
typedef __attribute__((ext_vector_type(4))) float f32x4;

constexpr int Mdim = 8192;
constexpr int Ndim = 11008;
constexpr int Kdim = 4096;

#define BK 32
#define NTILES 128          // Kdim / BK
#define TA 8192             // A-tile elems: 256 rows * 32
#define TB 4096             // B-tile elems: 128 rows * 32

__device__ __forceinline__ u16 f2bf(float f) {
  union { float f; unsigned u; } c; c.f = f;
  unsigned r = c.u + 0x7FFFu + ((c.u >> 16) & 1u);  // RTNE
  return (u16)(r >> 16);
}

// ---------------- kernel 1: group-dequant weight -> bf16 ----------------
__global__ __launch_bounds__(256) void k_dequant_w(const float* __restrict__ w,
                                                   u16* __restrict__ wb) {
  const int lane = threadIdx.x & 63;
  const long g = (long)blockIdx.x * 4 + (threadIdx.x >> 6);
  const long base = g * 128 + lane * 2;
  const float2 v = *(const float2*)(w + base);
  float mn = fminf(v.x, v.y), mx = fmaxf(v.x, v.y);
#pragma unroll
  for (int off = 32; off > 0; off >>= 1) {
    mn = fminf(mn, __shfl_xor(mn, off));
    mx = fmaxf(mx, __shfl_xor(mx, off));
  }
  const float scale = (mx - mn) / 15.0f;
  const float zp = -mn / scale;
  const u16 o0 = f2bf((v.x - zp) * scale);
  const u16 o1 = f2bf((v.y - zp) * scale);
  *(unsigned*)(wb + base) = (unsigned)o0 | ((unsigned)o1 << 16);
}

// ---------------- kernel 2: x f32 -> bf16 ----------------
__global__ __launch_bounds__(256) void k_cvt_x(const float* __restrict__ x,
                                               u16* __restrict__ xb) {
  const long i = ((long)blockIdx.x * 256 + threadIdx.x) * 8;
  const float4 v0 = *(const float4*)(x + i);
  const float4 v1 = *(const float4*)(x + i + 4);
  ushort8 o;
  o[0] = f2bf(v0.x); o[1] = f2bf(v0.y); o[2] = f2bf(v0.z); o[3] = f2bf(v0.w);
  o[4] = f2bf(v1.x); o[5] = f2bf(v1.y); o[6] = f2bf(v1.z); o[7] = f2bf(v1.w);
  *(ushort8*)(xb + i) = o;
}

// ---------------- kernel 3: 256x128-tile bf16 GEMM, 2 blocks/CU ----------------
__device__ __forceinline__ void async_ld16(const u16* g, u16* l) {
  __builtin_amdgcn_global_load_lds(
      (const __attribute__((address_space(1))) void*)g,
      (__attribute__((address_space(3))) void*)l, 16, 0, 0);
}

__global__ __launch_bounds__(256, 2) void k_gemm(const u16* __restrict__ A,
                                                 const u16* __restrict__ B,
                                                 const float* __restrict__ bias,
                                                 float* __restrict__ C) {
  __shared__ u16 As[3 * TA];   // 48 KB: 3-ring of A K-tiles (256x32)
  __shared__ u16 Bs[3 * TB];   // 24 KB: 3-ring of B K-tiles (128x32)

  const int t = threadIdx.x;
  const int wave = t >> 6;        // 0..3
  const int lane = t & 63;
  const int wm = wave >> 1;       // 2(M) x 2(N) wave grid; wave owns 128x64 out
  const int wn = wave & 1;
  const int r  = lane & 15;
  const int kg = lane >> 4;
  const int slot = kg ^ ((r >> 1) & 3);   // XOR bank swizzle (proven 0-conflict)

  // bijective XCD swizzle: 2752 workgroups = 8 XCDs x 344
  const int bid = blockIdx.x;
  const int wg = (bid & 7) * 344 + (bid >> 3);
  const int by = wg / 86;         // 0..31  (M tiles of 256)
  const int bx = wg % 86;         // 0..85  (N tiles of 128)
  const long bm0 = (long)by * 256;
  const long bn0 = (long)bx * 128;

  // staging: one issue = 256 thr x 16B = 4 KB = 64 rows of 32 cols.
  // A-tile = 4 issues, B-tile = 2 issues (6 per tile per wave -> vmcnt units).
  const int s_row  = t >> 2;                      // 0..63
  const int s_slot = (t & 3) ^ ((t >> 3) & 3);    // source pre-swizzle (rule 21)
  const u16* a_src = A + (bm0 + s_row) * Kdim + s_slot * 8;
  const u16* b_src = B + (bn0 + s_row) * Kdim + s_slot * 8;
  const int st_off = wave * 512;  // per-wave uniform LDS base within an issue

  const int a_roff = (wm * 128 + r) * 32 + slot * 8;  // + mf*512, mf=0..7
  const int b_roff = (wn * 64  + r) * 32 + slot * 8;  // + nf*512, nf=0..3

  f32x4 acc[8][4] = {};

#define STAGE(TAU, BUF) do {                                      \
    const u16* ga_ = a_src + (size_t)(TAU) * 32;                  \
    u16* la_ = As + (BUF) * TA + st_off;                          \
    async_ld16(ga_,                      la_);                    \
    async_ld16(ga_ + (size_t) 64 * Kdim, la_ + 2048);             \
    async_ld16(ga_ + (size_t)128 * Kdim, la_ + 4096);             \
    async_ld16(ga_ + (size_t)192 * Kdim, la_ + 6144);             \
    const u16* gb_ = b_src + (size_t)(TAU) * 32;                  \
    u16* lb_ = Bs + (BUF) * TB + st_off;                          \
    async_ld16(gb_,                      lb_);                    \
    async_ld16(gb_ + (size_t) 64 * Kdim, lb_ + 2048);             \
  } while (0)

#define VM6 asm volatile("s_waitcnt vmcnt(6)" ::: "memory")
#define VM0 asm volatile("s_waitcnt vmcnt(0)" ::: "memory")
#define VMNONE (void)0

  // Hazard ledger (3-ring, 1 barrier + 1 counted vmcnt per tile):
  //  - STAGE(t+2 -> buf (t+2)%3 == (t-1)%3) issued after barrier B_{t-1};
  //    buf (t-1)%3's reads all completed before B_{t-1} (each wave's ds_reads
  //    are lgkm-consumed by its MFMAs before it reaches the barrier). Safe.
  //  - Reads of tile t+1 execute after B_t. Its 6 loads (issued at top of
  //    tile t-1... tracked per-wave) are drained by VM6 at end of tile t
  //    (leaves only tile t+2's 6 outstanding); B_t then propagates all
  //    waves' drains. Safe.
  //  - Steady state: 12 outstanding before VM6, 6 after. Epilogue: VM0 at
  //    end of tile 126 drains tile 127's loads.
#define KTILE(TAU, BUF, DO_STAGE, VMSTMT) do {                               \
    if (DO_STAGE) STAGE((TAU) + 2, ((BUF) + 2) % 3);                         \
    const u16* Ab_ = As + (BUF) * TA;                                        \
    const u16* Bb_ = Bs + (BUF) * TB;                                        \
    short8 af[8], bfr[4];                                                    \
    _Pragma("unroll")                                                        \
    for (int mf = 0; mf < 8; ++mf) af[mf] = *(const short8*)&Ab_[a_roff + mf*512]; \
    _Pragma("unroll")                                                        \
    for (int nf = 0; nf < 4; ++nf) bfr[nf] = *(const short8*)&Bb_[b_roff + nf*512]; \
    __builtin_amdgcn_s_setprio(1);                                           \
    _Pragma("unroll")                                                        \
    for (int mf = 0; mf < 8; ++mf)                                           \
      _Pragma("unroll")                                                      \
      for (int nf = 0; nf < 4; ++nf)                                         \
        acc[mf][nf] = __builtin_amdgcn_mfma_f32_16x16x32_bf16(af[mf], bfr[nf], acc[mf][nf], 0, 0, 0); \
    __builtin_amdgcn_s_setprio(0);                                           \
    VMSTMT;                                                                  \
    __builtin_amdgcn_s_barrier();                                            \
  } while (0)

  // prologue: stage tiles 0,1 (12 loads/wave in flight), land tile 0
  STAGE(0, 0);
  STAGE(1, 1);
  VM6;                            // drain tile 0's 6 loads
  __builtin_amdgcn_s_barrier();

  // main loop: tiles 0..125 in unrolled groups of 3 (ring period)
  for (int tau = 0; tau < NTILES - 2; tau += 3) {
    KTILE(tau + 0, 0, 1, VM6);
    KTILE(tau + 1, 1, 1, VM6);
    KTILE(tau + 2, 2, 1, VM6);
  }
  // tau ran 0..123 -> covered tiles 0..125 (42 groups); staged through 127.
  KTILE(126, 0, 0, VM0);
  KTILE(127, 1, 0, VMNONE);

  // epilogue: C/D layout col = lane&15, row = (lane>>4)*4 + j
#pragma unroll
  for (int nf = 0; nf < 4; ++nf) {
    const long col = bn0 + wn * 64 + nf * 16 + r;
    const float bv = bias[col];
#pragma unroll
    for (int mf = 0; mf < 8; ++mf) {
      const long row0 = bm0 + wm * 128 + mf * 16 + kg * 4;
#pragma unroll
      for (int j = 0; j < 4; ++j)
        C[(row0 + j) * Ndim + col] = acc[mf][nf][j] + bv;
    }
  }
}

extern "C" void kernel_launch(void* const* d_in, const int* in_sizes, int n_in,
                              void* d_out, int out_size, void* d_ws, size_t ws_size,
                              hipStream_t stream) {
  const float* x    = (const float*)d_in[0];
  const float* w    = (const float*)d_in[1];
  const float* bias = (const float*)d_in[2];
  float* out = (float*)d_out;

  const size_t xb_elems = (size_t)Mdim * Kdim;
  const size_t wb_elems = (size_t)Ndim * Kdim;
  const size_t need = (xb_elems + wb_elems) * sizeof(u16);
  if (ws_size < need) {
    fprintf(stderr, "kernel_launch: ws too small (%zu < %zu)\n", ws_size, need);
    return;
  }
  u16* xb = (u16*)d_ws;
  u16* wb = xb + xb_elems;

  k_dequant_w<<<(int)(wb_elems / 128 / 4), 256, 0, stream>>>(w, wb);
  k_cvt_x<<<(int)(xb_elems / (8 * 256)), 256, 0, stream>>>(x, xb);

  // grid: 32 M-tiles x 86 N-tiles = 2752 blocks (divisible by 8 XCDs)
  k_gemm<<<(Mdim / 256) * (Ndim / 128), 256, 0, stream>>>(xb, wb, bias, out);
}

// Round 6
// 878.309 us; speedup vs baseline: 1.0324x; 1.0214x over previous
//
#include <hip/hip_runtime.h>
#include <hip/hip_bf16.h>
#include <stdio.h>

// BNBQuantizedLinear: out = x @ dequant(w)^T + bias
// x [8192,4096] f32, w [11008,4096] f32 (group-128 affine fake-quant), out f32.
// Round 6: sub-phase software pipeline. Each K-tile = SP0 + SP1; each sub-phase
// runs {16 MFMA on operands read LAST sub-phase; sched_barrier(0); ds_reads for
// NEXT sub-phase; stage; [vmcnt(6)]; s_barrier}. First MFMA of every sub-phase
// has zero lgkm wait -> LDS reads overlap MFMA pipe drain. Race-free (unlike
// round 4): prefetch of buf(tau+1) sits AFTER the mid-tile vmcnt(6)+barrier
// that guarantees its staging. 256x256 tile, BK=32, 4-ring LDS (128 KB),
// T1 XCD swizzle, T2 source-side XOR swizzle (0 conflicts measured).

typedef unsigned short u16;
typedef __attribute__((ext_vector_type(8))) short short8;
typedef __attribute__((ext_vector_type(8))) unsigned short ushort8;
typedef __attribute__((ext_vector_type(4))) float f32x4;

constexpr int Mdim = 8192;
constexpr int Ndim = 11008;
constexpr int Kdim = 4096;

#define BK 32
#define NTILES 128          // Kdim / BK
#define TILE_ELEMS 8192     // 256 rows * 32 cols u16 per K-tile buffer (16 KB)

__device__ __forceinline__ u16 f2bf(float f) {
  union { float f; unsigned u; } c; c.f = f;
  unsigned r = c.u + 0x7FFFu + ((c.u >> 16) & 1u);  // RTNE
  return (u16)(r >> 16);
}

// ---------------- kernel 1: group-dequant weight -> bf16 ----------------
__global__ __launch_bounds__(256) void k_dequant_w(const float* __restrict__ w,
                                                   u16* __restrict__ wb) {
  const int lane = threadIdx.x & 63;
  const long g = (long)blockIdx.x * 4 + (threadIdx.x >> 6);
  const long base = g * 128 + lane * 2;
  const float2 v = *(const float2*)(w + base);
  float mn = fminf(v.x, v.y), mx = fmaxf(v.x, v.y);
#pragma unroll
  for (int off = 32; off > 0; off >>= 1) {
    mn = fminf(mn, __shfl_xor(mn, off));
    mx = fmaxf(mx, __shfl_xor(mx, off));
  }
  const float scale = (mx - mn) / 15.0f;
  const float zp = -mn / scale;
  const u16 o0 = f2bf((v.x - zp) * scale);
  const u16 o1 = f2bf((v.y - zp) * scale);
  *(unsigned*)(wb + base) = (unsigned)o0 | ((unsigned)o1 << 16);
}

// ---------------- kernel 2: x f32 -> bf16 ----------------
__global__ __launch_bounds__(256) void k_cvt_x(const float* __restrict__ x,
                                               u16* __restrict__ xb) {
  const long i = ((long)blockIdx.x * 256 + threadIdx.x) * 8;
  const float4 v0 = *(const float4*)(x + i);
  const float4 v1 = *(const float4*)(x + i + 4);
  ushort8 o;
  o[0] = f2bf(v0.x); o[1] = f2bf(v0.y); o[2] = f2bf(v0.z); o[3] = f2bf(v0.w);
  o[4] = f2bf(v1.x); o[5] = f2bf(v1.y); o[6] = f2bf(v1.z); o[7] = f2bf(v1.w);
  *(ushort8*)(xb + i) = o;
}

// ---------------- kernel 3: sub-phase-pipelined 256x256 bf16 GEMM ----------------
__device__ __forceinline__ void async_ld16(const u16* g, u16* l) {
  __builtin_amdgcn_global_load_lds(
      (const __attribute__((address_space(1))) void*)g,
      (__attribute__((address_space(3))) void*)l, 16, 0, 0);
}

__global__ __launch_bounds__(512, 2) void k_gemm(const u16* __restrict__ A,
                                                 const u16* __restrict__ B,
                                                 const float* __restrict__ bias,
                                                 float* __restrict__ C) {
  __shared__ u16 As[4 * TILE_ELEMS];   // 64 KB: 4-ring of A K-tiles
  __shared__ u16 Bs[4 * TILE_ELEMS];   // 64 KB

  const int t = threadIdx.x;
  const int wave = t >> 6;        // 0..7
  const int lane = t & 63;
  const int wm = wave >> 2;       // 2(M) x 4(N); wave owns 128x64 out
  const int wn = wave & 3;
  const int r  = lane & 15;
  const int kg = lane >> 4;
  const int slot = kg ^ ((r >> 1) & 3);

  // bijective XCD swizzle: 1376 workgroups = 8 XCDs x 172
  const int bid = blockIdx.x;
  const int wg = (bid & 7) * 172 + (bid >> 3);
  const int by = wg / 43;
  const int bx = wg % 43;
  const long bm0 = (long)by * 256;
  const long bn0 = (long)bx * 256;

  // staging: one issue = 512 thr x 16B = 8 KB = 128 rows of 32 cols.
  const int s_row  = t >> 2;
  const int s_slot = (t & 3) ^ ((t >> 3) & 3);    // source pre-swizzle (rule 21)
  const u16* a_src = A + (bm0 + s_row) * Kdim + s_slot * 8;
  const u16* b_src = B + (bn0 + s_row) * Kdim + s_slot * 8;
  const int st_off = wave * 512;

  const int a_roff = (wm * 128 + r) * 32 + slot * 8;  // + mf*512
  const int b_roff = (wn * 64  + r) * 32 + slot * 8;  // + nf*512

  f32x4 acc[8][4] = {};
  short8 af[8];            // af[0..3](tau) read SP1 of tau-1; af[4..7](tau) read SP0 of tau
  short8 bf0[4], bf1[4];   // B frags double-buffered by tile parity

#define STAGE_A(TAU, BUF) do {                                    \
    const u16* g_ = a_src + (size_t)(TAU) * 32;                   \
    u16* l_ = As + (BUF) * TILE_ELEMS + st_off;                   \
    async_ld16(g_, l_);                                           \
    async_ld16(g_ + (size_t)128 * Kdim, l_ + 4096);               \
  } while (0)
#define STAGE_B(TAU, BUF) do {                                    \
    const u16* g_ = b_src + (size_t)(TAU) * 32;                   \
    u16* l_ = Bs + (BUF) * TILE_ELEMS + st_off;                   \
    async_ld16(g_, l_);                                           \
    async_ld16(g_ + (size_t)128 * Kdim, l_ + 4096);               \
  } while (0)

#define VM6 asm volatile("s_waitcnt vmcnt(6)" ::: "memory")
#define VM4 asm volatile("s_waitcnt vmcnt(4)" ::: "memory")
#define VM0 asm volatile("s_waitcnt vmcnt(0)" ::: "memory")
#define VMNONE (void)0
#define SB __builtin_amdgcn_sched_barrier(0)

  // Hazard ledger (per-wave loads: A:2 @SP0, B:2 @SP1 of each staging tile):
  //  RAW: reads of buf(tau+1) (SP1 prefetch + next tile's SP0 af47) occur after
  //    mid-tau's vmcnt(6)+barrier. At mid-tau outstanding = {A,B}(tau+1):4,
  //    {A,B}(tau+2):... precisely [A(t+1),B(t+1),A(t+2),B(t+2),A(t+3)] = 10;
  //    vmcnt(6) keeps newest 6 = {A(t+2),B(t+2),A(t+3)}, drains {A,B}(tau+1). OK
  //  WAR: STAGE_A(tau+3)->ring slot (tau-1)&3 at SP0 of tau: all waves' reads of
  //    buf(tau-1) completed before end-barrier(tau-1) (consumed by their MFMAs).
  //    STAGE_B same at SP1, additionally behind mid-barrier(tau). OK
  //  Reg WAR: prefetch overwrites af[0..3]/bfNXT after MFMA-1 issued (compiler
  //    tracks VGPR deps); af[4..7] overwritten next tile after MFMA-2 issued. OK
#define KTILE(TAU, BUF, BCUR, BNXT, DO_STAGE, VMSTMT, DO_PREF) do {          \
    const u16* Ac_ = As + (BUF) * TILE_ELEMS;                                \
    /* ---- SP0: MFMA half 1 (operands from tau-1's SP1 reads) ---- */       \
    __builtin_amdgcn_s_setprio(1);                                           \
    _Pragma("unroll")                                                        \
    for (int mf = 0; mf < 4; ++mf)                                           \
      _Pragma("unroll")                                                      \
      for (int nf = 0; nf < 4; ++nf)                                         \
        acc[mf][nf] = __builtin_amdgcn_mfma_f32_16x16x32_bf16(af[mf], BCUR[nf], acc[mf][nf], 0, 0, 0); \
    __builtin_amdgcn_s_setprio(0);                                           \
    SB;                                                                      \
    _Pragma("unroll")                                                        \
    for (int mf = 4; mf < 8; ++mf)                                           \
      af[mf] = *(const short8*)&Ac_[a_roff + mf*512];                        \
    if (DO_STAGE) STAGE_A((TAU) + 3, ((BUF) + 3) & 3);                       \
    VMSTMT;                                                                  \
    __builtin_amdgcn_s_barrier();  /* mid: buf(tau+1) now visible */         \
    /* ---- SP1: MFMA half 2 (af[4..7] read in SP0) ---- */                  \
    __builtin_amdgcn_s_setprio(1);                                           \
    _Pragma("unroll")                                                        \
    for (int mf = 4; mf < 8; ++mf)                                           \
      _Pragma("unroll")                                                      \
      for (int nf = 0; nf < 4; ++nf)                                         \
        acc[mf][nf] = __builtin_amdgcn_mfma_f32_16x16x32_bf16(af[mf], BCUR[nf], acc[mf][nf], 0, 0, 0); \
    __builtin_amdgcn_s_setprio(0);                                           \
    SB;                                                                      \
    if (DO_PREF) {                                                           \
      const u16* An_ = As + (((BUF) + 1) & 3) * TILE_ELEMS;                  \
      const u16* Bn_ = Bs + (((BUF) + 1) & 3) * TILE_ELEMS;                  \
      _Pragma("unroll")                                                      \
      for (int mf = 0; mf < 4; ++mf)                                         \
        af[mf] = *(const short8*)&An_[a_roff + mf*512];                      \
      _Pragma("unroll")                                                      \
      for (int nf = 0; nf < 4; ++nf)                                         \
        BNXT[nf] = *(const short8*)&Bn_[b_roff + nf*512];                    \
    }                                                                        \
    if (DO_STAGE) STAGE_B((TAU) + 3, ((BUF) + 3) & 3);                       \
    __builtin_amdgcn_s_barrier();  /* end */                                 \
  } while (0)

  // prologue: stage tiles 0,1,2 (A,B interleaved -> 12 loads/wave)
  STAGE_A(0, 0); STAGE_B(0, 0);
  STAGE_A(1, 1); STAGE_B(1, 1);
  STAGE_A(2, 2); STAGE_B(2, 2);
  VM6;                            // drains A0,B0 (and A1's first pair) -> buf0 ready
  __builtin_amdgcn_s_barrier();
  {
    const u16* An_ = As;
    const u16* Bn_ = Bs;
#pragma unroll
    for (int mf = 0; mf < 4; ++mf) af[mf] = *(const short8*)&An_[a_roff + mf*512];
#pragma unroll
    for (int nf = 0; nf < 4; ++nf) bf0[nf] = *(const short8*)&Bn_[b_roff + nf*512];
  }

  // main loop: tiles 0..123 (31 groups of 4, ring-aligned), then tail 124..127
  for (int tau = 0; tau < NTILES - 4; tau += 4) {
    KTILE(tau + 0, 0, bf0, bf1, 1, VM6, 1);
    KTILE(tau + 1, 1, bf1, bf0, 1, VM6, 1);
    KTILE(tau + 2, 2, bf0, bf1, 1, VM6, 1);
    KTILE(tau + 3, 3, bf1, bf0, 1, VM6, 1);
  }
  KTILE(124, 0, bf0, bf1, 1, VM6,    1);   // stages tile 127
  KTILE(125, 1, bf1, bf0, 0, VM4,    1);
  KTILE(126, 2, bf0, bf1, 0, VM0,    1);
  KTILE(127, 3, bf1, bf0, 0, VMNONE, 0);

  // epilogue: C/D layout col = lane&15, row = (lane>>4)*4 + j
#pragma unroll
  for (int nf = 0; nf < 4; ++nf) {
    const long col = bn0 + wn * 64 + nf * 16 + r;
    const float bv = bias[col];
#pragma unroll
    for (int mf = 0; mf < 8; ++mf) {
      const long row0 = bm0 + wm * 128 + mf * 16 + kg * 4;
#pragma unroll
      for (int j = 0; j < 4; ++j)
        C[(row0 + j) * Ndim + col] = acc[mf][nf][j] + bv;
    }
  }
}

extern "C" void kernel_launch(void* const* d_in, const int* in_sizes, int n_in,
                              void* d_out, int out_size, void* d_ws, size_t ws_size,
                              hipStream_t stream) {
  const float* x    = (const float*)d_in[0];
  const float* w    = (const float*)d_in[1];
  const float* bias = (const float*)d_in[2];
  float* out = (float*)d_out;

  const size_t xb_elems = (size_t)Mdim * Kdim;
  const size_t wb_elems = (size_t)Ndim * Kdim;
  const size_t need = (xb_elems + wb_elems) * sizeof(u16);
  if (ws_size < need) {
    fprintf(stderr, "kernel_launch: ws too small (%zu < %zu)\n", ws_size, need);
    return;
  }
  u16* xb = (u16*)d_ws;
  u16* wb = xb + xb_elems;

  k_dequant_w<<<(int)(wb_elems / 128 / 4), 256, 0, stream>>>(w, wb);
  k_cvt_x<<<(int)(xb_elems / (8 * 256)), 256, 0, stream>>>(x, xb);

  k_gemm<<<(Ndim / 256) * (Mdim / 256), 512, 0, stream>>>(xb, wb, bias, out);
}